// Round 7
// baseline (35.000 us; speedup 1.0000x reference)
//
#include <hip/hip_runtime.h>
#include <math.h>

// Two-kernel split.
// A: cs[b*128+h][i] = (c,s) = 128-pt DFT of row (b,h) at freq i  (2 MB in d_ws)
// B: out[b,i,h,w] = (1/W)*( cos(2pi*i*w/W)*c + sin(2pi*i*w/W)*s )
//    one contiguous 64 KB plane per block -> fill-like pure store stream.

#define WDIM 128
#define BLK 256
#define PI_OVER_64 0.04908738521234052f   // 2*pi/128

typedef float vfloat4 __attribute__((ext_vector_type(4)));

__global__ __launch_bounds__(BLK) void kspace_cs_kernel(
    const float* __restrict__ in, float2* __restrict__ cs) {
    const int bh = blockIdx.x;             // 0..2047
    __shared__ float x[WDIM];
    __shared__ float cp[BLK];
    __shared__ float sp[BLK];

    const int t = threadIdx.x;
    if (t < WDIM) x[t] = in[(size_t)bh * WDIM + t];

    const int i    = t & 127;
    const int half = t >> 7;               // 0/1
    const int base = half << 6;            // 0/64

    const float a0 = (float)((i * base) & 127) * PI_OVER_64;
    float C = __cosf(a0);
    float S = __sinf(a0);
    const float as = (float)i * PI_OVER_64;
    const float stC = __cosf(as);
    const float stS = __sinf(as);
    __syncthreads();

    float cc = 0.0f, ss = 0.0f;
    #pragma unroll
    for (int k = 0; k < 64; ++k) {
        const float xv = x[base + k];      // wave-uniform broadcast
        cc = fmaf(xv, C, cc);
        ss = fmaf(xv, S, ss);
        const float nC = fmaf(C, stC, -(S * stS));
        const float nS = fmaf(S, stC,  (C * stS));
        C = nC; S = nS;
    }
    cp[t] = cc; sp[t] = ss;
    __syncthreads();
    if (t < WDIM) {
        float2 v;
        v.x = cp[t] + cp[t + 128];
        v.y = sp[t] + sp[t + 128];
        cs[(size_t)bh * WDIM + t] = v;     // coalesced 8B/lane
    }
}

__global__ __launch_bounds__(BLK) void kspace_write_kernel(
    const float2* __restrict__ cs, float* __restrict__ out) {
    const int blk = blockIdx.x;            // b*128 + i  (consecutive planes)
    const int i = blk & 127;
    const int b = blk >> 7;

    __shared__ float2 csl[WDIM];

    const int t = threadIdx.x;
    // stage this plane's 128 (c,s) pairs: cs[(b*128+h)*128 + i], h = t
    if (t < WDIM)
        csl[t] = cs[(((size_t)b << 7) + t) * WDIM + i];

    const int col = t & 31;
    const int r   = t >> 5;                // 0..7
    const int w0  = col << 2;              // 0,4,...,124

    const float as = (float)i * PI_OVER_64;
    const float stC = __cosf(as);
    const float stS = __sinf(as);
    const int j0 = (i * w0) & 127;
    const float a0 = (float)j0 * PI_OVER_64;
    const float Cv0 = __cosf(a0);
    const float Sv0 = __sinf(a0);
    const float Cv1 = fmaf(Cv0, stC, -(Sv0 * stS));
    const float Sv1 = fmaf(Sv0, stC,  (Cv0 * stS));
    const float Cv2 = fmaf(Cv1, stC, -(Sv1 * stS));
    const float Sv2 = fmaf(Sv1, stC,  (Cv1 * stS));
    const float Cv3 = fmaf(Cv2, stC, -(Sv2 * stS));
    const float Sv3 = fmaf(Sv2, stC,  (Cv2 * stS));
    const float invW = 1.0f / (float)WDIM;

    __syncthreads();

    float* op = out + ((size_t)blk << 14); // contiguous 64 KB plane
    #pragma unroll
    for (int ii = 0; ii < 16; ++ii) {
        const int hp = (ii << 3) + r;      // 0..127
        const float2 v2 = csl[hp];         // broadcast read, conflict-free
        const float ci = v2.x * invW;
        const float si = v2.y * invW;
        vfloat4 v;
        v.x = fmaf(ci, Cv0, si * Sv0);
        v.y = fmaf(ci, Cv1, si * Sv1);
        v.z = fmaf(ci, Cv2, si * Sv2);
        v.w = fmaf(ci, Cv3, si * Sv3);
        *reinterpret_cast<vfloat4*>(op + (hp << 7) + w0) = v;
    }
}

extern "C" void kernel_launch(void* const* d_in, const int* in_sizes, int n_in,
                              void* d_out, int out_size, void* d_ws, size_t ws_size,
                              hipStream_t stream) {
    const float* in = (const float*)d_in[0];   // (16,1,128,128) fp32
    float* out = (float*)d_out;                // (16,128,128,128) fp32
    float2* cs = (float2*)d_ws;                // 2048*128*8 B = 2 MB scratch

    hipLaunchKernelGGL(kspace_cs_kernel, dim3(2048), dim3(BLK), 0, stream, in, cs);
    hipLaunchKernelGGL(kspace_write_kernel, dim3(16 * 128), dim3(BLK), 0, stream, cs, out);
}

// Round 8
// 27.600 us; speedup vs baseline: 1.2681x; 1.2681x over previous
//
#include <hip/hip_runtime.h>
#include <math.h>

// out[b,i,h,w] = (1/W)*( cos(2pi*i*w/W)*c[b,h,i] + sin(2pi*i*w/W)*s[b,h,i] )
// c,s = per-row 128-pt DFT components. Single kernel, block = (row-pair, i-quarter):
// stages 2 input rows (1 KB, no duplication), computes c,s for 2 rows x 32 freqs
// (shuffle quad-reduction, 2 barriers total), stores 32 KB as 1KB-contiguous
// wave stores. Phase 2 has ZERO transcendentals per iteration (all rotations).

#define WDIM 128
#define BLK 256
#define PI_OVER_64 0.04908738521234052f   // 2*pi/128

typedef float vfloat4 __attribute__((ext_vector_type(4)));

__global__ __launch_bounds__(BLK) void kspace_map_kernel(
    const float* __restrict__ in, float* __restrict__ out) {
    const int blk = blockIdx.x;       // 0..4095
    const int q   = blk & 3;          // i-quarter
    const int rp  = blk >> 2;         // row-pair 0..1023
    const int bh0 = rp << 1;
    const int b   = bh0 >> 7;
    const int h0  = bh0 & 127;

    __shared__ float x2[2][WDIM];
    __shared__ float cS[2][32];
    __shared__ float sS[2][32];

    const int t = threadIdx.x;

    // stage 2 input rows: 256 threads = 2 rows x 128 cols
    {
        const int srow = t >> 7, scol = t & 127;
        x2[srow][scol] = in[((size_t)bh0 + srow) * WDIM + scol];
    }

    // phase-1 mapping: u = t>>2 -> (row, il); seg = t&3 (in-wave quad)
    const int seg = t & 3;
    const int u   = t >> 2;
    const int row = u >> 5;           // wave-uniform
    const int il  = u & 31;
    const int ig1 = (q << 5) + il;
    const int k0  = seg << 5;         // 0,32,64,96

    // trig setup before the barrier (hides staging latency)
    const float a0p = (float)((ig1 * k0) & 127) * PI_OVER_64;
    float C = __cosf(a0p);
    float S = __sinf(a0p);
    const float asp = (float)ig1 * PI_OVER_64;
    const float stC = __cosf(asp);
    const float stS = __sinf(asp);

    __syncthreads();

    {
        float cc = 0.f, ss = 0.f;
        #pragma unroll
        for (int k = 0; k < 32; ++k) {
            const float xv = x2[row][k0 + k];
            cc = fmaf(xv, C, cc);
            ss = fmaf(xv, S, ss);
            const float nC = fmaf(C, stC, -(S * stS));
            const float nS = fmaf(S, stC,  (C * stS));
            C = nC; S = nS;
        }
        // quad reduction over seg (lanes t^1, t^2 share u)
        cc += __shfl_xor(cc, 1); ss += __shfl_xor(ss, 1);
        cc += __shfl_xor(cc, 2); ss += __shfl_xor(ss, 2);
        if (seg == 0) { cS[row][il] = cc; sS[row][il] = ss; }
    }
    __syncthreads();

    // ---- phase 2: 8 iterations, each wave stores 1 KB contiguous ----
    const float invW = 1.0f / (float)WDIM;
    const int lane = t & 63;
    const int wv   = t >> 6;          // 0..3
    const int col  = lane & 31;
    const int hpar = lane >> 5;       // row parity within pair
    const int w0   = col << 2;
    const int il0  = wv << 3;
    const int ig0  = (q << 5) + il0;

    // (Cv,Sv): angle ig*w0, advanced per-ii by w0-angle (wC,wS)
    // (tC,tS): angle ig (w-step), advanced per-ii by unit angle (oC,oS const)
    const float av = (float)((ig0 * w0) & 127) * PI_OVER_64;
    float Cv = __cosf(av);
    float Sv = __sinf(av);
    const float wA = (float)w0 * PI_OVER_64;
    const float wC = __cosf(wA);
    const float wS = __sinf(wA);
    float tC = __cosf((float)ig0 * PI_OVER_64);
    float tS = __sinf((float)ig0 * PI_OVER_64);
    const float oC = 0.99879545620517241f;   // cos(2*pi/128)
    const float oS = 0.049067674327418015f;  // sin(2*pi/128)

    float* op = out + ((size_t)b << 21) + ((size_t)ig0 << 14)
                    + ((size_t)(h0 + hpar) << 7) + w0;

    #pragma unroll
    for (int ii = 0; ii < 8; ++ii) {
        const int ilc = il0 + ii;
        const float ci = cS[hpar][ilc] * invW;   // 2-addr broadcast per wave
        const float si = sS[hpar][ilc] * invW;

        vfloat4 v;
        v.x = fmaf(ci, Cv, si * Sv);
        float c1 = fmaf(Cv, tC, -(Sv * tS)), s1 = fmaf(Sv, tC, Cv * tS);
        v.y = fmaf(ci, c1, si * s1);
        float c2 = fmaf(c1, tC, -(s1 * tS)), s2 = fmaf(s1, tC, c1 * tS);
        v.z = fmaf(ci, c2, si * s2);
        float c3 = fmaf(c2, tC, -(s2 * tS)), s3 = fmaf(s2, tC, c2 * tS);
        v.w = fmaf(ci, c3, si * s3);
        *reinterpret_cast<vfloat4*>(op) = v;
        op += (size_t)1 << 14;                   // next i-plane (64 KB)

        const float nCv = fmaf(Cv, wC, -(Sv * wS));
        const float nSv = fmaf(Sv, wC,  (Cv * wS));
        Cv = nCv; Sv = nSv;
        const float ntC = fmaf(tC, oC, -(tS * oS));
        const float ntS = fmaf(tS, oC,  (tC * oS));
        tC = ntC; tS = ntS;
    }
}

extern "C" void kernel_launch(void* const* d_in, const int* in_sizes, int n_in,
                              void* d_out, int out_size, void* d_ws, size_t ws_size,
                              hipStream_t stream) {
    const float* in = (const float*)d_in[0];   // (16,1,128,128) fp32
    float* out = (float*)d_out;                // (16,128,128,128) fp32
    dim3 grid(4096);                            // (row-pair, quarter)
    dim3 block(BLK);
    hipLaunchKernelGGL(kspace_map_kernel, grid, block, 0, stream, in, out);
}